// Round 7
// baseline (98.205 us; speedup 1.0000x reference)
//
#include <hip/hip_runtime.h>
#include <stdint.h>

// Expansion + checkerboard-preserving dropout.
// Phase 1: pack FINAL mask bits ((rand>0.25 | center) & in-bounds) into 3200 u32.
// Phase 2: block = (half-image, bc): stage 34 x rows (8.7KB) + 1600 mask words
//          (6.4KB) ONCE via global_load_lds; then 50 float4 stores per thread.
//          Column patterns have period 5 in the flat index -> 5 precomputed sets.

#define KEEP_SCALE (1.0f / 0.75f)

typedef float f32x4 __attribute__((ext_vector_type(4)));

__global__ __launch_bounds__(256) void build_mask_kernel(
    const float* __restrict__ rv,       // (320,320)
    uint32_t* __restrict__ mask)        // 3200 words, 10 per row
{
    int w = blockIdx.x * 256 + threadIdx.x;
    if (w >= 3200) return;
    int oh  = w / 10;
    int ow0 = (w - oh * 10) * 32;
    int qh = oh / 5, rh = oh - qh * 5;
    int ih = qh + rh - 2;
    bool hok = ((unsigned)ih < 64u);
    bool hc  = (rh == 2);
    const float* rp = rv + oh * 320 + ow0;
    uint32_t m = 0;
    #pragma unroll
    for (int b = 0; b < 32; ++b) {
        int ow = ow0 + b;
        int q = ow / 5, r = ow - q * 5;
        int iw = q + r - 2;
        bool keep = ((rp[b] > 0.25f) || (hc && (r == 2)))
                    && hok && ((unsigned)iw < 64u);
        m |= (uint32_t)keep << b;
    }
    mask[w] = m;
}

__global__ __launch_bounds__(256) void expand_cps_dropout_kernel(
    const float* __restrict__ x,        // (1024, 64, 64)
    const uint32_t* __restrict__ mask,  // 3200 words (bounds folded in)
    float* __restrict__ out)            // (1024, 320, 320)
{
    __shared__ __align__(16) float    xs[34 * 64];   // 8704 B: rows [s0, s0+34)
    __shared__ __align__(16) uint32_t ms[1600];      // 6400 B: half's mask words

    const int t    = threadIdx.x;       // 0..255
    const int half = blockIdx.x;        // 0: rows 0..159, 1: rows 160..319
    const int bc   = blockIdx.y;        // 0..1023
    const int s0   = half ? 30 : 0;     // first staged source row

    // ---- stage once per block: x = 544 16B-chunks, mask = 400 chunks ----
    const float* xsrc = x + (size_t)bc * 4096 + s0 * 64;
    __builtin_amdgcn_global_load_lds(
        (const __attribute__((address_space(1))) void*)(xsrc + t * 4),
        (__attribute__((address_space(3))) void*)(xs + (t & ~63) * 4), 16, 0, 0);
    __builtin_amdgcn_global_load_lds(
        (const __attribute__((address_space(1))) void*)(xsrc + (t + 256) * 4),
        (__attribute__((address_space(3))) void*)(xs + ((t + 256) & ~63) * 4), 16, 0, 0);
    if (t < 32) {
        __builtin_amdgcn_global_load_lds(
            (const __attribute__((address_space(1))) void*)(xsrc + (t + 512) * 4),
            (__attribute__((address_space(3))) void*)(xs + ((t + 512) & ~63) * 4), 16, 0, 0);
    }
    const uint32_t* msrc = mask + half * 1600;
    __builtin_amdgcn_global_load_lds(
        (const __attribute__((address_space(1))) void*)(msrc + t * 4),
        (__attribute__((address_space(3))) void*)(ms + (t & ~63) * 4), 16, 0, 0);
    if (t < 144) {
        __builtin_amdgcn_global_load_lds(
            (const __attribute__((address_space(1))) void*)(msrc + (t + 256) * 4),
            (__attribute__((address_space(3))) void*)(ms + ((t + 256) & ~63) * 4), 16, 0, 0);
    }
    __syncthreads();    // drains vmcnt, then barrier

    // ---- 5 column-pattern sets (flat index period: 256*5 = 1280 = 16 rows) ----
    int row0[5];
    int moffB[5];
    uint32_t msh_[5];
    int xoffB[5][4];
    int soffF[5];
    #pragma unroll
    for (int ji = 0; ji < 5; ++ji) {
        int f  = t + 256 * ji;          // 0..1279
        int r0 = f / 80;                // 0..15
        int o4 = f - r0 * 80;           // 0..79
        int ow = o4 * 4;
        row0[ji]  = r0;
        msh_[ji]  = (uint32_t)((o4 & 7) * 4);
        moffB[ji] = (r0 * 10 + (o4 >> 3)) * 4;
        soffF[ji] = r0 * 320 + ow;
        #pragma unroll
        for (int k = 0; k < 4; ++k) {
            int o = ow + k;
            int q = o / 5, r = o - q * 5;
            int iw = q + r - 2;
            iw = iw < 0 ? 0 : (iw > 63 ? 63 : iw);   // safe read; mask kills OOB
            xoffB[ji][k] = iw * 4;
        }
    }

    float* outh = out + (size_t)bc * 102400 + (size_t)half * 51200;
    const char* xsb = (const char*)xs;
    const char* msb = (const char*)ms;
    const int ohbase = half * 160;

    #pragma unroll 2
    for (int jj = 0; jj < 10; ++jj) {
        #pragma unroll
        for (int ji = 0; ji < 5; ++ji) {
            int row = row0[ji] + 16 * jj;      // 0..159 (half-local)
            int oh  = ohbase + row;
            int q   = oh / 5;
            int r   = oh - q * 5;
            int ih  = q + r - 2 - s0;          // staged-relative source row
            ih = ih < 0 ? 0 : (ih > 33 ? 33 : ih);
            const char* xr = xsb + ih * 256;
            uint32_t mb = *(const uint32_t*)(msb + moffB[ji] + jj * 640) >> msh_[ji];

            f32x4 o;
            o.x = (mb & 1u) ? *(const float*)(xr + xoffB[ji][0]) * KEEP_SCALE : 0.0f;
            o.y = (mb & 2u) ? *(const float*)(xr + xoffB[ji][1]) * KEEP_SCALE : 0.0f;
            o.z = (mb & 4u) ? *(const float*)(xr + xoffB[ji][2]) * KEEP_SCALE : 0.0f;
            o.w = (mb & 8u) ? *(const float*)(xr + xoffB[ji][3]) * KEEP_SCALE : 0.0f;
            *reinterpret_cast<f32x4*>(outh + soffF[ji] + jj * 5120) = o;
        }
    }
}

extern "C" void kernel_launch(void* const* d_in, const int* in_sizes, int n_in,
                              void* d_out, int out_size, void* d_ws, size_t ws_size,
                              hipStream_t stream) {
    const float* x  = (const float*)d_in[0];
    const float* rv = (const float*)d_in[1];
    float* out      = (float*)d_out;
    uint32_t* mask  = (uint32_t*)d_ws;      // 12.8 KB scratch

    hipLaunchKernelGGL(build_mask_kernel, dim3(13), dim3(256), 0, stream, rv, mask);

    dim3 block(256);
    dim3 grid(2, 1024);                     // (half, b*c)
    hipLaunchKernelGGL(expand_cps_dropout_kernel, grid, block, 0, stream,
                       x, mask, out);
}

// Round 8
// 98.049 us; speedup vs baseline: 1.0016x; 1.0016x over previous
//
#include <hip/hip_runtime.h>
#include <stdint.h>

// Expansion + checkerboard-preserving dropout.
// Phase 1: pack FINAL mask bits ((rand>0.25 | center) & in-bounds) into 3200 u32.
// Phase 2: persistent blocks, 4 tiles each. Block b -> fixed row-group g=b&7,
//          images bc = (b>>3) + 256*it. Mask words staged once (g fixed) and
//          hoisted to registers; x rows double-buffered in LDS with the next
//          tile's global_load_lds issued BEFORE computing the current tile.

#define KEEP_SCALE (1.0f / 0.75f)

typedef float f32x4 __attribute__((ext_vector_type(4)));

__global__ __launch_bounds__(256) void build_mask_kernel(
    const float* __restrict__ rv,       // (320,320)
    uint32_t* __restrict__ mask)        // 3200 words, 10 per row
{
    int w = blockIdx.x * 256 + threadIdx.x;
    if (w >= 3200) return;
    int oh  = w / 10;
    int ow0 = (w - oh * 10) * 32;
    int qh = oh / 5, rh = oh - qh * 5;
    int ih = qh + rh - 2;
    bool hok = ((unsigned)ih < 64u);
    bool hc  = (rh == 2);
    const float* rp = rv + oh * 320 + ow0;
    uint32_t m = 0;
    #pragma unroll
    for (int b = 0; b < 32; ++b) {
        int ow = ow0 + b;
        int q = ow / 5, r = ow - q * 5;
        int iw = q + r - 2;
        bool keep = ((rp[b] > 0.25f) || (hc && (r == 2)))
                    && hok && ((unsigned)iw < 64u);
        m |= (uint32_t)keep << b;
    }
    mask[w] = m;
}

__global__ __launch_bounds__(320) void expand_cps_dropout_kernel(
    const float* __restrict__ x,        // (1024, 64, 64)
    const uint32_t* __restrict__ mask,  // 3200 words (bounds folded in)
    float* __restrict__ out)            // (1024, 320, 320)
{
    __shared__ __align__(16) float    xs[2][12 * 64];  // 2 x 3072 B (double buffer)
    __shared__ __align__(16) uint32_t ms[400];         // 1600 B (staged once)

    const int t   = threadIdx.x;        // 0..319
    const int b   = blockIdx.x;         // 0..2047
    const int g   = b & 7;              // fixed 40-row group for this block
    const int bc0 = b >> 3;             // 0..255; tiles use bc0 + 256*it

    int s0 = 8 * g - 2;                 // first staged source row
    s0 = s0 < 0 ? 0 : (s0 > 52 ? 52 : s0);

    // ---- prologue staging: tile 0 x rows + mask words ----
    const float* xsrc0 = x + (size_t)bc0 * 4096 + s0 * 64;
    if (t < 192) {                      // 192 x 16B chunks (12 rows)
        __builtin_amdgcn_global_load_lds(
            (const __attribute__((address_space(1))) void*)(xsrc0 + t * 4),
            (__attribute__((address_space(3))) void*)(&xs[0][0] + (t & ~63) * 4),
            16, 0, 0);
    } else if (t < 292) {               // 100 x 16B chunks of mask
        int i = t - 192;
        const uint32_t* msrc = mask + g * 400;
        __builtin_amdgcn_global_load_lds(
            (const __attribute__((address_space(1))) void*)(msrc + i * 4),
            (__attribute__((address_space(3))) void*)(ms + (i & ~63) * 4),
            16, 0, 0);
    }

    // ---- per-thread patterns (no LDS dependency -> hides staging latency) ----
    const int ow4 = t % 80;
    const int ohL = t / 80;             // 0..3
    const int ow  = ow4 * 4;
    const int msh = (ow4 & 7) * 4;
    const int mwi = ow4 >> 3;

    int xoffB[4];                       // byte offset within a staged row
    #pragma unroll
    for (int k = 0; k < 4; ++k) {
        int o = ow + k;
        int q = o / 5, r = o - q * 5;
        int iw = q + r - 2;
        iw = iw < 0 ? 0 : (iw > 63 ? 63 : iw);   // safe read; mask kills OOB
        xoffB[k] = iw * 4;
    }
    int rowB[10];                       // staged-row byte offsets per store j
    #pragma unroll
    for (int j = 0; j < 10; ++j) {
        int oh = g * 40 + ohL + 4 * j;
        int q = oh / 5, r = oh - q * 5;
        int ihrel = q + r - 2 - s0;
        ihrel = ihrel < 0 ? 0 : (ihrel > 11 ? 11 : ihrel);
        rowB[j] = ihrel * 256;
    }
    float* outb = out + (size_t)bc0 * 102400 + (size_t)(g * 40 + ohL) * 320 + ow;

    __syncthreads();                    // drains vmcnt, then barrier

    // ---- hoist mask words to registers (shared by all 4 tiles) ----
    uint32_t mb[10];
    #pragma unroll
    for (int j = 0; j < 10; ++j)
        mb[j] = ms[(ohL + 4 * j) * 10 + mwi] >> msh;

    // ---- 4 tiles, double-buffered ----
    #pragma unroll
    for (int it = 0; it < 4; ++it) {
        // issue next tile's x staging into the other buffer BEFORE computing
        if (it < 3 && t < 192) {
            const float* xsrcn =
                x + (size_t)(bc0 + 256 * (it + 1)) * 4096 + s0 * 64;
            __builtin_amdgcn_global_load_lds(
                (const __attribute__((address_space(1))) void*)(xsrcn + t * 4),
                (__attribute__((address_space(3))) void*)(&xs[(it + 1) & 1][0] + (t & ~63) * 4),
                16, 0, 0);
        }

        const char* xb = (const char*)&xs[it & 1][0];
        float* op = outb + (size_t)it * 256 * 102400;

        #pragma unroll
        for (int j = 0; j < 10; ++j) {
            const char* xr = xb + rowB[j];
            uint32_t m = mb[j];
            f32x4 o;
            o.x = (m & 1u) ? *(const float*)(xr + xoffB[0]) * KEEP_SCALE : 0.0f;
            o.y = (m & 2u) ? *(const float*)(xr + xoffB[1]) * KEEP_SCALE : 0.0f;
            o.z = (m & 4u) ? *(const float*)(xr + xoffB[2]) * KEEP_SCALE : 0.0f;
            o.w = (m & 8u) ? *(const float*)(xr + xoffB[3]) * KEEP_SCALE : 0.0f;
            *reinterpret_cast<f32x4*>(op + (size_t)(4 * j) * 320) = o;
        }

        if (it < 3) __syncthreads();    // loads issued pre-compute have landed; free drain
    }
}

extern "C" void kernel_launch(void* const* d_in, const int* in_sizes, int n_in,
                              void* d_out, int out_size, void* d_ws, size_t ws_size,
                              hipStream_t stream) {
    const float* x  = (const float*)d_in[0];
    const float* rv = (const float*)d_in[1];
    float* out      = (float*)d_out;
    uint32_t* mask  = (uint32_t*)d_ws;      // 12.8 KB scratch

    hipLaunchKernelGGL(build_mask_kernel, dim3(13), dim3(256), 0, stream, rv, mask);

    dim3 block(320);
    dim3 grid(2048);                        // persistent-ish: 4 tiles per block
    hipLaunchKernelGGL(expand_cps_dropout_kernel, grid, block, 0, stream,
                       x, mask, out);
}

// Round 9
// 87.145 us; speedup vs baseline: 1.1269x; 1.1251x over previous
//
#include <hip/hip_runtime.h>
#include <stdint.h>

// Expansion + checkerboard-preserving dropout.
// Phase 1: pack FINAL mask bits ((rand>0.25 | center) & in-bounds) into 3200 u32.
// Phase 2: fill-shaped main kernel: 256-thread blocks, each block = 16 contiguous
//          output rows (20 KB), flat LINEAR block->address mapping, grid = 20480
//          = exactly 10 residency rounds. Stage 8 x rows + 160 mask words (168
//          16B chunks) via global_load_lds; 5 float4 stores per thread.

#define KEEP_SCALE (1.0f / 0.75f)

typedef float f32x4 __attribute__((ext_vector_type(4)));

__global__ __launch_bounds__(256) void build_mask_kernel(
    const float* __restrict__ rv,       // (320,320)
    uint32_t* __restrict__ mask)        // 3200 words, 10 per row
{
    int w = blockIdx.x * 256 + threadIdx.x;
    if (w >= 3200) return;
    int oh  = w / 10;
    int ow0 = (w - oh * 10) * 32;
    int qh = oh / 5, rh = oh - qh * 5;
    int ih = qh + rh - 2;
    bool hok = ((unsigned)ih < 64u);
    bool hc  = (rh == 2);
    const float* rp = rv + oh * 320 + ow0;
    uint32_t m = 0;
    #pragma unroll
    for (int b = 0; b < 32; ++b) {
        int ow = ow0 + b;
        int q = ow / 5, r = ow - q * 5;
        int iw = q + r - 2;
        bool keep = ((rp[b] > 0.25f) || (hc && (r == 2)))
                    && hok && ((unsigned)iw < 64u);
        m |= (uint32_t)keep << b;
    }
    mask[w] = m;
}

__global__ __launch_bounds__(256) void expand_cps_dropout_kernel(
    const float* __restrict__ x,        // (1024, 64, 64)
    const uint32_t* __restrict__ mask,  // 3200 words (bounds folded in)
    float* __restrict__ out)            // (1024, 320, 320)
{
    __shared__ __align__(16) float    xs[8 * 64];   // 2048 B: rows [s0, s0+8)
    __shared__ __align__(16) uint32_t ms[160];      // 640 B: 16 rows x 10 words

    const int t  = threadIdx.x;         // 0..255
    const int b  = blockIdx.x;          // 0..20479, LINEAR over output
    const int bc = b / 20;              // image
    const int rg = b - bc * 20;         // 16-row chunk within image

    const int a = 16 * rg;              // first output row of this block
    int s0 = a / 5 - 2;                 // first staged source row
    s0 = s0 < 0 ? 0 : (s0 > 56 ? 56 : s0);

    // ---- stage: x = 128 chunks (threads 0..127), mask = 40 chunks (128..167) ----
    if (t < 128) {
        const float* xsrc = x + (size_t)bc * 4096 + s0 * 64;
        __builtin_amdgcn_global_load_lds(
            (const __attribute__((address_space(1))) void*)(xsrc + t * 4),
            (__attribute__((address_space(3))) void*)(xs + (t & ~63) * 4),
            16, 0, 0);
    } else if (t < 168) {
        int i = t - 128;
        const uint32_t* msrc = mask + rg * 160;     // rows a..a+15 -> words a*10..
        __builtin_amdgcn_global_load_lds(
            (const __attribute__((address_space(1))) void*)(msrc + i * 4),
            (__attribute__((address_space(3))) void*)(ms + (i & ~63) * 4),
            16, 0, 0);
    }

    // ---- per-thread patterns for the 5 stores (computed during stage wait) ----
    int      xoffB[5][4];               // byte offsets within staged row
    int      rowB[5];                   // staged-row byte offset
    int      soffF[5];                  // output float offset within chunk
    int      midx[5];                   // mask word index
    uint32_t msh_[5];                   // shift within word
    #pragma unroll
    for (int ji = 0; ji < 5; ++ji) {
        int f  = t + 256 * ji;          // 0..1279 (block covers 1280 float4)
        int r0 = f / 80;                // local row 0..15
        int o4 = f - r0 * 80;           // float4 index in row
        int ow = o4 * 4;
        soffF[ji] = r0 * 320 + ow;
        msh_[ji]  = (uint32_t)((o4 & 7) * 4);
        midx[ji]  = r0 * 10 + (o4 >> 3);
        int oh = a + r0;
        int q = oh / 5, r = oh - q * 5;
        int ihrel = q + r - 2 - s0;
        ihrel = ihrel < 0 ? 0 : (ihrel > 7 ? 7 : ihrel);  // mask kills OOB
        rowB[ji] = ihrel * 256;
        #pragma unroll
        for (int k = 0; k < 4; ++k) {
            int o = ow + k;
            int qq = o / 5, rr = o - qq * 5;
            int iw = qq + rr - 2;
            iw = iw < 0 ? 0 : (iw > 63 ? 63 : iw);        // mask kills OOB
            xoffB[ji][k] = iw * 4;
        }
    }

    __syncthreads();                    // drains vmcnt, then barrier

    uint32_t mb[5];
    #pragma unroll
    for (int ji = 0; ji < 5; ++ji)
        mb[ji] = ms[midx[ji]] >> msh_[ji];

    float* ob = out + (size_t)b * 5120;       // linear 20 KB chunk
    const char* xsb = (const char*)xs;

    #pragma unroll
    for (int ji = 0; ji < 5; ++ji) {
        const char* xr = xsb + rowB[ji];
        uint32_t m = mb[ji];
        f32x4 o;
        o.x = (m & 1u) ? *(const float*)(xr + xoffB[ji][0]) * KEEP_SCALE : 0.0f;
        o.y = (m & 2u) ? *(const float*)(xr + xoffB[ji][1]) * KEEP_SCALE : 0.0f;
        o.z = (m & 4u) ? *(const float*)(xr + xoffB[ji][2]) * KEEP_SCALE : 0.0f;
        o.w = (m & 8u) ? *(const float*)(xr + xoffB[ji][3]) * KEEP_SCALE : 0.0f;
        *reinterpret_cast<f32x4*>(ob + soffF[ji]) = o;
    }
}

extern "C" void kernel_launch(void* const* d_in, const int* in_sizes, int n_in,
                              void* d_out, int out_size, void* d_ws, size_t ws_size,
                              hipStream_t stream) {
    const float* x  = (const float*)d_in[0];
    const float* rv = (const float*)d_in[1];
    float* out      = (float*)d_out;
    uint32_t* mask  = (uint32_t*)d_ws;      // 12.8 KB scratch

    hipLaunchKernelGGL(build_mask_kernel, dim3(13), dim3(256), 0, stream, rv, mask);

    dim3 block(256);
    dim3 grid(20480);                       // 1024 images x 20 chunks, linear
    hipLaunchKernelGGL(expand_cps_dropout_kernel, grid, block, 0, stream,
                       x, mask, out);
}